// Round 7
// baseline (81.781 us; speedup 1.0000x reference)
//
#include <hip/hip_runtime.h>
#include <math.h>

#define PI_F 3.14159265358979323846f

// d_ws layout (floats), NO memset (all read slots unconditionally written):
//   block blk of k_partial owns [blk*512, blk*512+512):
//     s  partials at [blk*512 + p]        (p = 0..195)
//     s2 partials at [blk*512 + 256 + p]
//   final stats float2[196] at ST_OFF = 1024*512.
#define BLK_STRIDE 512
#define ST_OFF (1024 * BLK_STRIDE)

// ---------------------------------------------------------------------------
// Kernel 1: per-patch partials. 1024 blocks x 256 thr, 4 images/block.
// LDS only 12.5 KB -> 4 blocks/CU, 16 waves/CU; ~3 independent float4
// loads/thread => ~49 KB in flight per CU => HBM/L3 BW-saturated staging
// (fix for R6's Little's-law stall at 1 block/CU). Stores coalesced
// (consecutive threads -> consecutive addresses). Zero atomics.
// ---------------------------------------------------------------------------
__global__ __launch_bounds__(256) void k_partial(const float* __restrict__ x,
                                                 float* __restrict__ ws) {
    __shared__ __align__(16) float sx[4 * 784];   // 12544 B
    const float4* x4 = (const float4*)x;
    const int base4 = blockIdx.x * 784;           // 4 images = 784 float4
    for (int i = threadIdx.x; i < 784; i += 256)
        ((float4*)sx)[i] = x4[base4 + i];
    __syncthreads();
    const int p = threadIdx.x;
    if (p < 196) {
        const int r = p / 14;
        const int off = 2 * p + 28 * r;           // even -> 8B aligned
        float s = 0.f, s2 = 0.f;
#pragma unroll
        for (int i = 0; i < 4; i++) {
            const float* b = sx + i * 784 + off;
            float2 t = *(const float2*)b;
            float2 u = *(const float2*)(b + 28);
            s += (t.x + t.y) + (u.x + u.y);
            s2 = fmaf(t.x, t.x, s2); s2 = fmaf(t.y, t.y, s2);
            s2 = fmaf(u.x, u.x, s2); s2 = fmaf(u.y, u.y, s2);
        }
        float* base = ws + blockIdx.x * BLK_STRIDE;
        base[p]       = s;    // coalesced across threads
        base[256 + p] = s2;
    }
}

// ---------------------------------------------------------------------------
// Kernel 2: finalize stats. 196 blocks x 256 thr; block p reduces its
// patch's 1024 partials (strided L2-hit loads), writes float2 stats.
// ---------------------------------------------------------------------------
__global__ __launch_bounds__(256) void k_reduce(float* __restrict__ ws) {
    const int p = blockIdx.x;
    const int tid = threadIdx.x;
    float s = 0.f, s2 = 0.f;
#pragma unroll
    for (int j = 0; j < 4; j++) {
        const float* base = ws + (tid + 256 * j) * BLK_STRIDE;
        s  += base[p];
        s2 += base[256 + p];
    }
#pragma unroll
    for (int off = 32; off > 0; off >>= 1) {
        s  += __shfl_down(s, off, 64);
        s2 += __shfl_down(s2, off, 64);
    }
    __shared__ float red[8];
    const int wave = tid >> 6;
    if ((tid & 63) == 0) { red[wave] = s; red[wave + 4] = s2; }
    __syncthreads();
    if (tid == 0) {
        float S  = (red[0] + red[1]) + (red[2] + red[3]);
        float S2 = (red[4] + red[5]) + (red[6] + red[7]);
        const float N = 16384.0f;
        float mean = S / N;
        float var = fmaxf((S2 - S * mean) / (N - 1.0f), 0.f);
        ((float2*)(ws + ST_OFF))[p] =
            make_float2(mean, PI_F / (sqrtf(var) + 1e-6f));
    }
}

// ---------------------------------------------------------------------------
// Kernel 3: features + GEMV + log_softmax. 512 blocks x 512 thr, 8 images
// per block (1/wave). Circuit reduced analytically (RZ phases cancel in
// |amp|^2; CNOTs permute basis (i,j,k,l)->(i,j,k^i,l^j)):
//   feats = [cos a0, cos a1, cos a0*cos a2, cos a1*cos a3]
// Patch-per-lane: 4 cos/patch (minimum), W via ds_read_b128 (16B aligned,
// lane-consecutive). LDS = 58 KB -> 2 blocks/CU, 16 waves/CU.
// ---------------------------------------------------------------------------
__global__ __launch_bounds__(512, 4) void k_main(const float* __restrict__ x,
                                                 const float* __restrict__ W,
                                                 const float* __restrict__ bias,
                                                 const float* __restrict__ ws,
                                                 float* __restrict__ out) {
    __shared__ __align__(16) float  sW[7840];     // raw W [10][784]
    __shared__ __align__(16) float  sx[8 * 784];
    __shared__ __align__(16) float2 sst[196];
    __shared__ float sbias[10];

    const int tid = threadIdx.x;
    const float4* W4 = (const float4*)W;
    for (int i = tid; i < 1960; i += 512)
        ((float4*)sW)[i] = W4[i];
    const float4* x4 = (const float4*)(x + (size_t)blockIdx.x * 8 * 784);
    for (int i = tid; i < 1568; i += 512)
        ((float4*)sx)[i] = x4[i];
    if (tid < 196)
        sst[tid] = ((const float2*)(ws + ST_OFF))[tid];  // HW kernel ordering
    if (tid < 10) sbias[tid] = bias[tid];
    __syncthreads();

    const int wave = tid >> 6;
    const int lane = tid & 63;
    const float* img = sx + wave * 784;

    float acc[10];
#pragma unroll
    for (int o = 0; o < 10; o++) acc[o] = 0.f;

#pragma unroll
    for (int k = 0; k < 4; k++) {
        const int p = lane + 64 * k;
        if (p < 196) {
            const int r = p / 14;
            const int off = 2 * p + 28 * r;
            float2 t = *(const float2*)(img + off);
            float2 u = *(const float2*)(img + off + 28);
            float2 ms = sst[p];
            float c0 = __cosf((t.x - ms.x) * ms.y);
            float c1 = __cosf((t.y - ms.x) * ms.y);
            float f2 = c0 * __cosf((u.x - ms.x) * ms.y);
            float f3 = c1 * __cosf((u.y - ms.x) * ms.y);
            const float* wp = sW + 4 * p;
#pragma unroll
            for (int o = 0; o < 10; o++) {
                float4 w = *(const float4*)(wp + o * 784);
                acc[o] += fmaf(c0, w.x, fmaf(c1, w.y,
                          fmaf(f2, w.z, f3 * w.w)));
            }
        }
    }

#pragma unroll
    for (int o = 0; o < 10; o++) {
#pragma unroll
        for (int off = 32; off > 0; off >>= 1)
            acc[o] += __shfl_down(acc[o], off, 64);
    }

    if (lane == 0) {
        float m = -INFINITY;
#pragma unroll
        for (int o = 0; o < 10; o++) { acc[o] += sbias[o]; m = fmaxf(m, acc[o]); }
        float ssum = 0.f;
#pragma unroll
        for (int o = 0; o < 10; o++) ssum += __expf(acc[o] - m);
        float lse = m + __logf(ssum);
        float* op = out + ((size_t)blockIdx.x * 8 + wave) * 10;
#pragma unroll
        for (int o = 0; o < 10; o++) op[o] = acc[o] - lse;
    }
}

extern "C" void kernel_launch(void* const* d_in, const int* in_sizes, int n_in,
                              void* d_out, int out_size, void* d_ws, size_t ws_size,
                              hipStream_t stream) {
    const float* x    = (const float*)d_in[0];
    // d_in[1] = params: provably unused (RZ phases cancel in |amp|^2)
    const float* W    = (const float*)d_in[2];
    const float* bias = (const float*)d_in[3];
    float* ws  = (float*)d_ws;
    float* out = (float*)d_out;

    hipLaunchKernelGGL(k_partial, dim3(1024), dim3(256), 0, stream, x, ws);
    hipLaunchKernelGGL(k_reduce,  dim3(196),  dim3(256), 0, stream, ws);
    hipLaunchKernelGGL(k_main,    dim3(512),  dim3(512), 0, stream,
                       x, W, bias, ws, out);
}